// Round 14
// baseline (231.347 us; speedup 1.0000x reference)
//
#include <hip/hip_runtime.h>
#include <hip/hip_bf16.h>
#include <stdint.h>

#define B_SZ   2
#define S_LEN  2048
#define DMODEL 2048
#define NH     16
#define DHD    128

typedef __attribute__((ext_vector_type(8))) __bf16 bf16x8;
typedef __attribute__((ext_vector_type(4))) float  f32x4;
typedef __attribute__((ext_vector_type(4))) float  float4v;
typedef __attribute__((ext_vector_type(8))) unsigned short ushort8;
typedef __attribute__((ext_vector_type(4))) unsigned short ushort4v;

__device__ __forceinline__ unsigned short f2bf(float f) {
  unsigned int u = __float_as_uint(f);
  unsigned int r = (u + 0x7fffu + ((u >> 16) & 1u)) >> 16;
  return (unsigned short)r;
}

__device__ __forceinline__ unsigned int cvt_pk_bf16(float lo, float hi) {
  unsigned int r;
  asm("v_cvt_pk_bf16_f32 %0, %1, %2" : "=v"(r) : "v"(lo), "v"(hi));
  return r;
}

__device__ __forceinline__ void async_cp16(void* lds, const void* g) {
  __builtin_amdgcn_global_load_lds(
      (const __attribute__((address_space(1))) void*)g,
      (__attribute__((address_space(3))) void*)lds, 16, 0, 0);
}

// ------- merged prep: weight transposes (0..4095), x cast (4096..12287),
//         rope table (12288..12799) -------
__global__ __launch_bounds__(256) void k_prep_all(const float* __restrict__ x,
                                                  const float* __restrict__ w0,
                                                  const float* __restrict__ w1,
                                                  const float* __restrict__ w2,
                                                  const float* __restrict__ w3,
                                                  unsigned short* __restrict__ xb,
                                                  unsigned short* __restrict__ WTbase,
                                                  float* __restrict__ cosT,
                                                  float* __restrict__ sinT) {
  __shared__ unsigned short tile[64 * 72];
  const int bx = blockIdx.x;
  const int t = threadIdx.x;
  if (bx < 4096) {
    const int z = bx >> 10;
    const int wi = bx & 1023;
    const float* W = (z == 0) ? w0 : (z == 1) ? w1 : (z == 2) ? w2 : w3;
    unsigned short* WT = WTbase + (size_t)z * 4194304;
    const int n0 = (wi & 31) * 64;
    const int k0 = (wi >> 5) * 64;
#pragma unroll
    for (int i = 0; i < 4; ++i) {
      int c = t + 256 * i;
      int r = c >> 4, c4 = c & 15;
      float4v v = *(const float4v*)(W + (size_t)(k0 + r) * DMODEL + n0 + c4 * 4);
      ushort4v o;
      o[0] = f2bf(v[0]); o[1] = f2bf(v[1]); o[2] = f2bf(v[2]); o[3] = f2bf(v[3]);
      *(ushort4v*)(&tile[r * 72 + c4 * 4]) = o;
    }
    __syncthreads();
#pragma unroll
    for (int i = 0; i < 2; ++i) {
      int c = t + 256 * i;
      int n = c >> 3, k8 = c & 7;
      ushort8 o;
#pragma unroll
      for (int j = 0; j < 8; ++j) o[j] = tile[(k8 * 8 + j) * 72 + n];
      *(ushort8*)(WT + (size_t)(n0 + n) * DMODEL + k0 + k8 * 8) = o;
    }
  } else if (bx < 12288) {
    int i = (bx - 4096) * 256 + t;  // < 2097152
    float4v v = ((const float4v*)x)[i];
    ushort4v o;
    o[0] = f2bf(v[0]); o[1] = f2bf(v[1]); o[2] = f2bf(v[2]); o[3] = f2bf(v[3]);
    ((ushort4v*)xb)[i] = o;
  } else {
    int i = (bx - 12288) * 256 + t;  // < S_LEN*64
    int s = i >> 6, dj = i & 63;
    float e = __expf(-9.210340371976184f * (float)dj * (1.0f / 64.0f));
    float f = (float)s * e;
    cosT[i] = cosf(f);
    sinT[i] = sinf(f);
  }
}

// ---------------- 128x128x64 2-phase look-ahead GEMM (R6 schedule, sq tile) ----
// 256 thr, 4 waves (2M x 2N), per-wave 64x64, acc[4][4]. LDS 2 x 32KB -> 2 blk/CU.
// Per tile: p0 reads k0 frags + STG_A(t+1); lgkm0; 8 MFMA; k1 reads; 8 MFMA;
// barrier; p1 lgkm0 + STG_B(t+2) + 16 MFMA + vmcnt(4); barrier.
// EPI 0: fp32 row-major.  EPI 1: fused QKV epilogue (RoPE on q/k), bf16 BHSD.
template <int EPI>
__global__ __launch_bounds__(256, 2) void k_gemm128sq(
    const unsigned short* __restrict__ A,
    const unsigned short* __restrict__ BT,
    float* __restrict__ C0,
    unsigned short* __restrict__ Cq,
    unsigned short* __restrict__ Ck,
    unsigned short* __restrict__ Cv,
    const float* __restrict__ cosT,
    const float* __restrict__ sinT,
    int chn) {
  __shared__ char smem[65536];
  const int tid = threadIdx.x;

  // 2-D XCD chunk swizzle: 8 XCDs as 2 (bm-halves of 16) x 4 (bn-quarters of chn)
  const int xcd = blockIdx.x & 7;
  const int idx = blockIdx.x >> 3;
  const int bm = (xcd >> 2) * 16 + (idx & 15);
  const int bn = (xcd & 3) * chn + (idx >> 4);

  const int gs = (tid & 7) ^ ((tid >> 3) & 7);
  const unsigned short* Abase = A + (size_t)(bm * 128 + (tid >> 3)) * 2048 + gs * 8;
  const unsigned short* Bbase = BT + (size_t)(bn * 128 + (tid >> 3)) * 2048 + gs * 8;
  const int dstA = tid * 16;
  const int dstB = 16384 + tid * 16;

  const int lane = tid & 63, wid = tid >> 6;
  const int wr = wid >> 1, wcn = wid & 1;
  const int lr = lane & 15, hi = lane >> 4;
  int aoff[4][2], boff[4][2];
#pragma unroll
  for (int m = 0; m < 4; ++m) {
    int row = wr * 64 + m * 16 + lr;
#pragma unroll
    for (int k = 0; k < 2; ++k)
      aoff[m][k] = row * 128 + ((((k * 4 + hi)) ^ (row & 7)) << 4);
  }
#pragma unroll
  for (int n = 0; n < 4; ++n) {
    int row = wcn * 64 + n * 16 + lr;
#pragma unroll
    for (int k = 0; k < 2; ++k)
      boff[n][k] = 16384 + row * 128 + ((((k * 4 + hi)) ^ (row & 7)) << 4);
  }

  f32x4 acc[4][4];
#pragma unroll
  for (int m = 0; m < 4; ++m)
#pragma unroll
    for (int n = 0; n < 4; ++n) {
      f32x4 z = {0.f, 0.f, 0.f, 0.f};
      acc[m][n] = z;
    }

#define STG_A(c, t_) do {                                                   \
    const unsigned short* _s = Abase + (t_) * 64;                           \
    async_cp16(smem + (c) * 32768 + dstA, _s);                              \
    async_cp16(smem + (c) * 32768 + dstA + 4096, _s + 32 * 2048);           \
    async_cp16(smem + (c) * 32768 + dstA + 8192, _s + 64 * 2048);           \
    async_cp16(smem + (c) * 32768 + dstA + 12288, _s + 96 * 2048);          \
  } while (0)
#define STG_B(c, t_) do {                                                   \
    const unsigned short* _s = Bbase + (t_) * 64;                           \
    async_cp16(smem + (c) * 32768 + dstB, _s);                              \
    async_cp16(smem + (c) * 32768 + dstB + 4096, _s + 32 * 2048);           \
    async_cp16(smem + (c) * 32768 + dstB + 8192, _s + 64 * 2048);           \
    async_cp16(smem + (c) * 32768 + dstB + 12288, _s + 96 * 2048);          \
  } while (0)

  auto tile = [&](int T, int CC, bool DO_A, bool DO_B, int VM) __attribute__((always_inline)) {
    const char* Sb = smem + CC * 32768;
    bf16x8 a0[4], b0[4], a1[4], b1[4];
#pragma unroll
    for (int m = 0; m < 4; ++m) a0[m] = *(const bf16x8*)(Sb + aoff[m][0]);
#pragma unroll
    for (int n = 0; n < 4; ++n) b0[n] = *(const bf16x8*)(Sb + boff[n][0]);
    if (DO_A) STG_A(CC ^ 1, T + 1);
    asm volatile("s_waitcnt lgkmcnt(0)" ::: "memory");
    __builtin_amdgcn_sched_barrier(0);
    __builtin_amdgcn_s_setprio(1);
#pragma unroll
    for (int m = 0; m < 4; ++m) {
      acc[m][0] = __builtin_amdgcn_mfma_f32_16x16x32_bf16(a0[m], b0[0], acc[m][0], 0, 0, 0);
      acc[m][1] = __builtin_amdgcn_mfma_f32_16x16x32_bf16(a0[m], b0[1], acc[m][1], 0, 0, 0);
    }
    __builtin_amdgcn_s_setprio(0);
    __builtin_amdgcn_sched_barrier(0);
    // k1 reads issue here, hidden under the second MFMA half
#pragma unroll
    for (int m = 0; m < 4; ++m) a1[m] = *(const bf16x8*)(Sb + aoff[m][1]);
#pragma unroll
    for (int n = 0; n < 4; ++n) b1[n] = *(const bf16x8*)(Sb + boff[n][1]);
    __builtin_amdgcn_sched_barrier(0);
    __builtin_amdgcn_s_setprio(1);
#pragma unroll
    for (int m = 0; m < 4; ++m) {
      acc[m][2] = __builtin_amdgcn_mfma_f32_16x16x32_bf16(a0[m], b0[2], acc[m][2], 0, 0, 0);
      acc[m][3] = __builtin_amdgcn_mfma_f32_16x16x32_bf16(a0[m], b0[3], acc[m][3], 0, 0, 0);
    }
    __builtin_amdgcn_s_setprio(0);
    __builtin_amdgcn_s_barrier();
    __builtin_amdgcn_sched_barrier(0);
    asm volatile("s_waitcnt lgkmcnt(0)" ::: "memory");
    __builtin_amdgcn_sched_barrier(0);
    if (DO_B) STG_B(CC, T + 2);
    __builtin_amdgcn_s_setprio(1);
#pragma unroll
    for (int m = 0; m < 4; ++m)
#pragma unroll
      for (int n = 0; n < 4; ++n)
        acc[m][n] = __builtin_amdgcn_mfma_f32_16x16x32_bf16(a1[m], b1[n], acc[m][n], 0, 0, 0);
    __builtin_amdgcn_s_setprio(0);
    if (VM == 0) asm volatile("s_waitcnt vmcnt(4)" ::: "memory");
    else if (VM == 1) asm volatile("s_waitcnt vmcnt(0)" ::: "memory");
    if (VM != 2) {
      __builtin_amdgcn_s_barrier();
      __builtin_amdgcn_sched_barrier(0);
    }
  };

  STG_B(0, 0);
  STG_A(0, 0);
  STG_B(1, 1);
  asm volatile("s_waitcnt vmcnt(4)" ::: "memory");
  __builtin_amdgcn_s_barrier();
  __builtin_amdgcn_sched_barrier(0);

  for (int it = 0; it < 15; ++it) {
    tile(2 * it, 0, true, true, 0);
    tile(2 * it + 1, 1, true, true, 0);
  }
  tile(30, 0, true, false, 1);
  tile(31, 1, false, false, 2);

  // ---- epilogue ----
  const int row_b = bm * 128 + wr * 64 + hi * 4;
  const int col_b = bn * 128 + wcn * 64 + lr;
  if (EPI == 0) {
#pragma unroll
    for (int m = 0; m < 4; ++m)
#pragma unroll
      for (int n = 0; n < 4; ++n) {
        int col = col_b + n * 16;
#pragma unroll
        for (int j = 0; j < 4; ++j) {
          int row = row_b + m * 16 + j;
          C0[(size_t)row * 2048 + col] = acc[m][n][j];
        }
      }
  } else {
#pragma unroll
    for (int m = 0; m < 4; ++m) {
#pragma unroll
      for (int n = 0; n < 4; ++n) {
        int col = col_b + n * 16;
        int sel = col >> 11;  // 0:q 1:k 2:v
        int hh = (col >> 7) & 15, d = col & 127;
        if (sel == 2) {
#pragma unroll
          for (int j = 0; j < 4; ++j) {
            int row = row_b + m * 16 + j;
            int b = row >> 11, s = row & 2047;
            Cv[((size_t)(b * NH + hh) * S_LEN + s) * DHD + d] = f2bf(acc[m][n][j]);
          }
        } else {
          unsigned short* dst = sel ? Ck : Cq;
          int dj = d >> 1;
          float sgn = (d & 1) ? 1.f : -1.f;
#pragma unroll
          for (int j = 0; j < 4; ++j) {
            int row = row_b + m * 16 + j;
            int b = row >> 11, s = row & 2047;
            float v = acc[m][n][j];
            float pp = __shfl_xor(v, 1);
            float cc = cosT[(s << 6) + dj];
            float sn = sinT[(s << 6) + dj];
            dst[((size_t)(b * NH + hh) * S_LEN + s) * DHD + d] = f2bf(v * cc + sgn * pp * sn);
          }
        }
      }
    }
  }
#undef STG_A
#undef STG_B
}

// ---------------- causal flash attention (R9 body: XCD-local head mapping) ----
__global__ __launch_bounds__(256) void k_flash_attn(const unsigned short* __restrict__ Qg,
                                                    const unsigned short* __restrict__ Kg,
                                                    const unsigned short* __restrict__ Vg,
                                                    unsigned short* __restrict__ Og) {
  __shared__ unsigned short K_lds[2][64 * 128];
  __shared__ unsigned short VT_lds[2][128 * 64];

  const int lid = blockIdx.x;
  const int pq = (lid >> 3) & 15;
  const int hb = ((lid >> 7) << 3) | (lid & 7);
  const int h = hb & 15, b = hb >> 4;

  const int t = threadIdx.x;
  const int lane = t & 63, wave = t >> 6;
  const int hi = lane >> 4, lr = lane & 15;

  const size_t head = (size_t)(b * NH + h) * (size_t)(S_LEN * DHD);
  const unsigned short* Q = Qg + head;
  const unsigned short* Kp = Kg + head;
  const unsigned short* Vp = Vg + head;

  const int kr0 = t >> 4;
  const int kgc = (t & 15) ^ (kr0 & 7);
  const unsigned short* Kbase = Kp + (size_t)kr0 * DHD + kgc * 8;
  const int kdst = t * 16;

  const int vdc = t & 15, vsp0 = t >> 4;
  const unsigned short* Vbase = Vp + (size_t)(2 * vsp0) * DHD + vdc * 8;
  const int bo0 = 16 * ((vsp0 >> 1) & 3) + 8 * ((vsp0 >> 3) & 1) + 4 * (vsp0 & 1);

  const float sc = 0.08838834764831845f;  // 1/sqrt(128)

  for (int pass = 0; pass < 2; ++pass) {
    const int qt = (pass == 0) ? pq : (31 - pq);
    const int nt = qt + 1;
    const int qbase = qt * 64 + wave * 16;
    const int qrow = qbase + lr;

    bf16x8 qf[4];
    {
      const unsigned short* qr_ = Q + (size_t)(qbase + lr) * DHD;
#pragma unroll
      for (int kc = 0; kc < 4; ++kc) qf[kc] = *(const bf16x8*)(qr_ + kc * 32 + hi * 8);
    }

    f32x4 of[8];
#pragma unroll
    for (int i = 0; i < 8; ++i) {
      f32x4 z = {0.f, 0.f, 0.f, 0.f};
      of[i] = z;
    }
    float mS = -INFINITY;
    float lsum = 0.f;

    {
#pragma unroll
      for (int i = 0; i < 4; ++i)
        async_cp16((char*)K_lds[0] + kdst + i * 4096, Kbase + (size_t)(16 * i) * DHD);
      ushort8 va0 = *(const ushort8*)(Vbase);
      ushort8 vb0 = *(const ushort8*)(Vbase + DHD);
      ushort8 va1 = *(const ushort8*)(Vbase + (size_t)32 * DHD);
      ushort8 vb1 = *(const ushort8*)(Vbase + (size_t)33 * DHD);
#pragma unroll
      for (int j = 0; j < 8; ++j) {
        int row = vdc * 8 + j;
        int swz = ((j ^ vdc) & 7) << 4;
        *(unsigned int*)((char*)VT_lds[0] + row * 128 + (bo0 ^ swz)) =
            (unsigned int)va0[j] | ((unsigned int)vb0[j] << 16);
        *(unsigned int*)((char*)VT_lds[0] + row * 128 + ((bo0 | 64) ^ swz)) =
            (unsigned int)va1[j] | ((unsigned int)vb1[j] << 16);
      }
    }
    __syncthreads();

    for (int tt = 0; tt < nt; ++tt) {
      const int cur = tt & 1;
      const int kv0 = tt * 64;
      const bool more = (tt + 1 < nt);
      const bool diag = (tt == qt);

      ushort8 va0, vb0, va1, vb1;
      if (more) {
        const unsigned short* ks = Kbase + (size_t)(kv0 + 64) * DHD;
#pragma unroll
        for (int i = 0; i < 4; ++i)
          async_cp16((char*)K_lds[cur ^ 1] + kdst + i * 4096, ks + (size_t)(16 * i) * DHD);
        const unsigned short* vs = Vbase + (size_t)(kv0 + 64) * DHD;
        va0 = *(const ushort8*)(vs);
        vb0 = *(const ushort8*)(vs + DHD);
        va1 = *(const ushort8*)(vs + (size_t)32 * DHD);
        vb1 = *(const ushort8*)(vs + (size_t)33 * DHD);
      }

      const char* Kb = (const char*)K_lds[cur];
      f32x4 sf[4];
#pragma unroll
      for (int n = 0; n < 4; ++n) {
        f32x4 z = {0.f, 0.f, 0.f, 0.f};
        sf[n] = z;
      }
      __builtin_amdgcn_s_setprio(1);
#pragma unroll
      for (int n = 0; n < 4; ++n) {
        const int kr = n * 16 + lr;
        const int kswz = (kr & 7) << 4;
#pragma unroll
        for (int kc = 0; kc < 4; ++kc) {
          bf16x8 kf = *(const bf16x8*)(Kb + kr * 256 + ((kc * 64 + hi * 16) ^ kswz));
          sf[n] = __builtin_amdgcn_mfma_f32_16x16x32_bf16(kf, qf[kc], sf[n], 0, 0, 0);
        }
      }
      __builtin_amdgcn_s_setprio(0);

      float p[4][4];
      float mx = -INFINITY;
      if (diag) {
#pragma unroll
        for (int n = 0; n < 4; ++n)
#pragma unroll
          for (int j = 0; j < 4; ++j) {
            int kvcol = kv0 + n * 16 + hi * 4 + j;
            float v = (kvcol > qrow) ? -INFINITY : sf[n][j];
            p[n][j] = v;
            mx = fmaxf(mx, v);
          }
      } else {
#pragma unroll
        for (int n = 0; n < 4; ++n)
#pragma unroll
          for (int j = 0; j < 4; ++j) {
            float v = sf[n][j];
            p[n][j] = v;
            mx = fmaxf(mx, v);
          }
      }
      mx = fmaxf(mx, __shfl_xor(mx, 16));
      mx = fmaxf(mx, __shfl_xor(mx, 32));
      float mn = fmaxf(mS, mx);
      float corr = __expf((mS - mn) * sc);
      mS = mn;
      float mns = mn * sc;
      float rs = 0.f;
#pragma unroll
      for (int n = 0; n < 4; ++n)
#pragma unroll
        for (int j = 0; j < 4; ++j) {
          float e = __expf(__builtin_fmaf(p[n][j], sc, -mns));
          p[n][j] = e;
          rs += e;
        }
      rs += __shfl_xor(rs, 16);
      rs += __shfl_xor(rs, 32);
      lsum = lsum * corr + rs;

      unsigned int pk[4][2];
#pragma unroll
      for (int n = 0; n < 4; ++n) {
        pk[n][0] = cvt_pk_bf16(p[n][0], p[n][1]);
        pk[n][1] = cvt_pk_bf16(p[n][2], p[n][3]);
      }

      float corrb[4];
#pragma unroll
      for (int j = 0; j < 4; ++j) corrb[j] = __shfl(corr, hi * 4 + j);
#pragma unroll
      for (int nd = 0; nd < 8; ++nd)
#pragma unroll
        for (int j = 0; j < 4; ++j) of[nd][j] *= corrb[j];

      const char* Vb = (const char*)VT_lds[cur];
      __builtin_amdgcn_s_setprio(1);
#pragma unroll
      for (int kc = 0; kc < 2; ++kc) {
        union { unsigned int u[4]; bf16x8 v; } pa;
        pa.u[0] = pk[2 * kc][0];
        pa.u[1] = pk[2 * kc][1];
        pa.u[2] = pk[2 * kc + 1][0];
        pa.u[3] = pk[2 * kc + 1][1];
#pragma unroll
        for (int nd = 0; nd < 8; ++nd) {
          const int vr = nd * 16 + lr;
          const int vswz = ((vr & 7) ^ ((vr >> 3) & 7)) << 4;
          bf16x8 vf = *(const bf16x8*)(Vb + vr * 128 + ((kc * 64 + hi * 16) ^ vswz));
          of[nd] = __builtin_amdgcn_mfma_f32_16x16x32_bf16(pa.v, vf, of[nd], 0, 0, 0);
        }
      }
      __builtin_amdgcn_s_setprio(0);

      if (more) {
        char* Vw = (char*)VT_lds[cur ^ 1];
#pragma unroll
        for (int j = 0; j < 8; ++j) {
          int row = vdc * 8 + j;
          int swz = ((j ^ vdc) & 7) << 4;
          *(unsigned int*)(Vw + row * 128 + (bo0 ^ swz)) =
              (unsigned int)va0[j] | ((unsigned int)vb0[j] << 16);
          *(unsigned int*)(Vw + row * 128 + ((bo0 | 64) ^ swz)) =
              (unsigned int)va1[j] | ((unsigned int)vb1[j] << 16);
        }
      }
      __syncthreads();
    }

    float inv[4];
#pragma unroll
    for (int j = 0; j < 4; ++j) {
      float ls = __shfl(lsum, hi * 4 + j);
      inv[j] = 1.0f / ls;
    }
#pragma unroll
    for (int nd = 0; nd < 8; ++nd)
#pragma unroll
      for (int j = 0; j < 4; ++j) {
        int qr = qbase + hi * 4 + j;
        Og[((size_t)(b * S_LEN + qr) * NH + h) * DHD + nd * 16 + lr] = f2bf(of[nd][j] * inv[j]);
      }
  }
}

// ---------------- launch ----------------
extern "C" void kernel_launch(void* const* d_in, const int* in_sizes, int n_in,
                              void* d_out, int out_size, void* d_ws, size_t ws_size,
                              hipStream_t stream) {
  const float* x  = (const float*)d_in[0];
  const float* wq = (const float*)d_in[1];
  const float* wk = (const float*)d_in[2];
  const float* wv = (const float*)d_in[3];
  const float* wo = (const float*)d_in[4];
  float* out = (float*)d_out;

  char* ws = (char*)d_ws;
  unsigned short* xb    = (unsigned short*)(ws);              // 16 MB (reused as attn out)
  unsigned short* wqT   = (unsigned short*)(ws + 16777216);   // 8 MB each -> [6144][2048]
  unsigned short* woT   = (unsigned short*)(ws + 41943040);
  unsigned short* qb    = (unsigned short*)(ws + 50331648);   // 16 MB each
  unsigned short* kb    = (unsigned short*)(ws + 67108864);
  unsigned short* vb    = (unsigned short*)(ws + 83886080);
  float*          cosT  = (float*)(ws + 100663296);           // 512 KB
  float*          sinT  = (float*)(ws + 101187584);
  unsigned short* attnb = xb;

  k_prep_all<<<12800, 256, 0, stream>>>(x, wq, wk, wv, wo, xb, wqT, cosT, sinT);

  // fused q/k/v projection: 32x48 tiles of 128x128 -> 1536 blocks (6/CU even)
  k_gemm128sq<1><<<1536, 256, 0, stream>>>(xb, wqT, nullptr, qb, kb, vb, cosT, sinT, 12);

  // attention: 512 blocks, XCD-local head mapping (lid%8 = hb&7)
  k_flash_attn<<<512, 256, 0, stream>>>(qb, kb, vb, attnb);

  // output projection: 32x16 tiles of 128x128 -> 512 blocks (2/CU even)
  k_gemm128sq<0><<<512, 256, 0, stream>>>(attnb, woT, out, nullptr, nullptr, nullptr,
                                          nullptr, nullptr, 4);
}

// Round 15
// 226.122 us; speedup vs baseline: 1.0231x; 1.0231x over previous
//
#include <hip/hip_runtime.h>
#include <hip/hip_bf16.h>
#include <stdint.h>

#define B_SZ   2
#define S_LEN  2048
#define DMODEL 2048
#define NH     16
#define DHD    128

typedef __attribute__((ext_vector_type(8))) __bf16 bf16x8;
typedef __attribute__((ext_vector_type(4))) float  f32x4;
typedef __attribute__((ext_vector_type(4))) float  float4v;
typedef __attribute__((ext_vector_type(8))) unsigned short ushort8;
typedef __attribute__((ext_vector_type(4))) unsigned short ushort4v;

__device__ __forceinline__ unsigned short f2bf(float f) {
  unsigned int u = __float_as_uint(f);
  unsigned int r = (u + 0x7fffu + ((u >> 16) & 1u)) >> 16;
  return (unsigned short)r;
}

__device__ __forceinline__ unsigned int cvt_pk_bf16(float lo, float hi) {
  unsigned int r;
  asm("v_cvt_pk_bf16_f32 %0, %1, %2" : "=v"(r) : "v"(lo), "v"(hi));
  return r;
}

__device__ __forceinline__ void async_cp16(void* lds, const void* g) {
  __builtin_amdgcn_global_load_lds(
      (const __attribute__((address_space(1))) void*)g,
      (__attribute__((address_space(3))) void*)lds, 16, 0, 0);
}

// ------- merged prep: weight transposes (0..4095), x cast (4096..12287),
//         rope table (12288..12799) -------
__global__ __launch_bounds__(256) void k_prep_all(const float* __restrict__ x,
                                                  const float* __restrict__ w0,
                                                  const float* __restrict__ w1,
                                                  const float* __restrict__ w2,
                                                  const float* __restrict__ w3,
                                                  unsigned short* __restrict__ xb,
                                                  unsigned short* __restrict__ WTbase,
                                                  float* __restrict__ cosT,
                                                  float* __restrict__ sinT) {
  __shared__ unsigned short tile[64 * 72];
  const int bx = blockIdx.x;
  const int t = threadIdx.x;
  if (bx < 4096) {
    const int z = bx >> 10;
    const int wi = bx & 1023;
    const float* W = (z == 0) ? w0 : (z == 1) ? w1 : (z == 2) ? w2 : w3;
    unsigned short* WT = WTbase + (size_t)z * 4194304;
    const int n0 = (wi & 31) * 64;
    const int k0 = (wi >> 5) * 64;
#pragma unroll
    for (int i = 0; i < 4; ++i) {
      int c = t + 256 * i;
      int r = c >> 4, c4 = c & 15;
      float4v v = *(const float4v*)(W + (size_t)(k0 + r) * DMODEL + n0 + c4 * 4);
      ushort4v o;
      o[0] = f2bf(v[0]); o[1] = f2bf(v[1]); o[2] = f2bf(v[2]); o[3] = f2bf(v[3]);
      *(ushort4v*)(&tile[r * 72 + c4 * 4]) = o;
    }
    __syncthreads();
#pragma unroll
    for (int i = 0; i < 2; ++i) {
      int c = t + 256 * i;
      int n = c >> 3, k8 = c & 7;
      ushort8 o;
#pragma unroll
      for (int j = 0; j < 8; ++j) o[j] = tile[(k8 * 8 + j) * 72 + n];
      *(ushort8*)(WT + (size_t)(n0 + n) * DMODEL + k0 + k8 * 8) = o;
    }
  } else if (bx < 12288) {
    int i = (bx - 4096) * 256 + t;  // < 2097152
    float4v v = ((const float4v*)x)[i];
    ushort4v o;
    o[0] = f2bf(v[0]); o[1] = f2bf(v[1]); o[2] = f2bf(v[2]); o[3] = f2bf(v[3]);
    ((ushort4v*)xb)[i] = o;
  } else {
    int i = (bx - 12288) * 256 + t;  // < S_LEN*64
    int s = i >> 6, dj = i & 63;
    float e = __expf(-9.210340371976184f * (float)dj * (1.0f / 64.0f));
    float f = (float)s * e;
    cosT[i] = cosf(f);
    sinT[i] = sinf(f);
  }
}

// ---------------- 128x256x64 2-phase look-ahead GEMM (R9 proven body) ----
// EPI 0: fp32 row-major.  EPI 1: fused QKV epilogue (RoPE on q/k), bf16 BHSD.
template <int EPI>
__global__ __launch_bounds__(512, 2) void k_gemm128(
    const unsigned short* __restrict__ A,
    const unsigned short* __restrict__ BT,
    float* __restrict__ C0,
    unsigned short* __restrict__ Cq,
    unsigned short* __restrict__ Ck,
    unsigned short* __restrict__ Cv,
    const float* __restrict__ cosT,
    const float* __restrict__ sinT,
    int chn) {
  __shared__ char smem[98304];
  const int tid = threadIdx.x;

  // 2-D XCD chunk swizzle: 8 XCDs as 2 (bm) x 4 (bn); chunk = 16bm x chn bn
  const int xcd = blockIdx.x & 7;
  const int idx = blockIdx.x >> 3;
  const int bm = (xcd >> 2) * 16 + (idx & 15);
  const int bn = (xcd & 3) * chn + (idx >> 4);

  const int gs = (tid & 7) ^ ((tid >> 3) & 7);
  const unsigned short* Abase = A + (size_t)(bm * 128 + (tid >> 3)) * 2048 + gs * 8;
  const unsigned short* Bbase = BT + (size_t)(bn * 256 + (tid >> 3)) * 2048 + gs * 8;
  const int dstA = tid * 16;
  const int dstB = 16384 + tid * 16;

  const int lane = tid & 63, wid = tid >> 6;
  const int wr = wid >> 2, wcn = wid & 3;
  const int lr = lane & 15, hi = lane >> 4;
  int aoff[4][2], boff[4][2];
#pragma unroll
  for (int m = 0; m < 4; ++m) {
    int row = wr * 64 + m * 16 + lr;
#pragma unroll
    for (int k = 0; k < 2; ++k)
      aoff[m][k] = row * 128 + ((((k * 4 + hi)) ^ (row & 7)) << 4);
  }
#pragma unroll
  for (int n = 0; n < 4; ++n) {
    int row = wcn * 64 + n * 16 + lr;
#pragma unroll
    for (int k = 0; k < 2; ++k)
      boff[n][k] = 16384 + row * 128 + ((((k * 4 + hi)) ^ (row & 7)) << 4);
  }

  f32x4 acc[4][4];
#pragma unroll
  for (int m = 0; m < 4; ++m)
#pragma unroll
    for (int n = 0; n < 4; ++n) {
      f32x4 z = {0.f, 0.f, 0.f, 0.f};
      acc[m][n] = z;
    }

#define STG_A(c, t_) do {                                                   \
    const unsigned short* _s = Abase + (t_) * 64;                           \
    async_cp16(smem + (c) * 49152 + dstA, _s);                              \
    async_cp16(smem + (c) * 49152 + dstA + 8192, _s + 64 * 2048);           \
  } while (0)
#define STG_B(c, t_) do {                                                   \
    const unsigned short* _s = Bbase + (t_) * 64;                           \
    async_cp16(smem + (c) * 49152 + dstB, _s);                              \
    async_cp16(smem + (c) * 49152 + dstB + 8192, _s + 64 * 2048);           \
    async_cp16(smem + (c) * 49152 + dstB + 16384, _s + 128 * 2048);         \
    async_cp16(smem + (c) * 49152 + dstB + 24576, _s + 192 * 2048);         \
  } while (0)

  auto tile = [&](int T, int CC, bool DO_A, bool DO_B, int VM) __attribute__((always_inline)) {
    const char* Sb = smem + CC * 49152;
    bf16x8 a0[4], b0[4], a1[4], b1[4];
#pragma unroll
    for (int m = 0; m < 4; ++m) a0[m] = *(const bf16x8*)(Sb + aoff[m][0]);
#pragma unroll
    for (int n = 0; n < 4; ++n) b0[n] = *(const bf16x8*)(Sb + boff[n][0]);
    if (DO_A) STG_A(CC ^ 1, T + 1);
    asm volatile("s_waitcnt lgkmcnt(0)" ::: "memory");
    __builtin_amdgcn_sched_barrier(0);
    __builtin_amdgcn_s_setprio(1);
#pragma unroll
    for (int m = 0; m < 4; ++m) {
      acc[m][0] = __builtin_amdgcn_mfma_f32_16x16x32_bf16(a0[m], b0[0], acc[m][0], 0, 0, 0);
      acc[m][1] = __builtin_amdgcn_mfma_f32_16x16x32_bf16(a0[m], b0[1], acc[m][1], 0, 0, 0);
    }
    __builtin_amdgcn_s_setprio(0);
    __builtin_amdgcn_sched_barrier(0);
    // k1 reads issue here, hidden under the second MFMA half
#pragma unroll
    for (int m = 0; m < 4; ++m) a1[m] = *(const bf16x8*)(Sb + aoff[m][1]);
#pragma unroll
    for (int n = 0; n < 4; ++n) b1[n] = *(const bf16x8*)(Sb + boff[n][1]);
    __builtin_amdgcn_sched_barrier(0);
    __builtin_amdgcn_s_setprio(1);
#pragma unroll
    for (int m = 0; m < 4; ++m) {
      acc[m][2] = __builtin_amdgcn_mfma_f32_16x16x32_bf16(a0[m], b0[2], acc[m][2], 0, 0, 0);
      acc[m][3] = __builtin_amdgcn_mfma_f32_16x16x32_bf16(a0[m], b0[3], acc[m][3], 0, 0, 0);
    }
    __builtin_amdgcn_s_setprio(0);
    __builtin_amdgcn_s_barrier();
    __builtin_amdgcn_sched_barrier(0);
    asm volatile("s_waitcnt lgkmcnt(0)" ::: "memory");
    __builtin_amdgcn_sched_barrier(0);
    if (DO_B) STG_B(CC, T + 2);
    __builtin_amdgcn_s_setprio(1);
#pragma unroll
    for (int m = 0; m < 4; ++m)
#pragma unroll
      for (int n = 0; n < 4; ++n)
        acc[m][n] = __builtin_amdgcn_mfma_f32_16x16x32_bf16(a1[m], b1[n], acc[m][n], 0, 0, 0);
    __builtin_amdgcn_s_setprio(0);
    if (VM == 0) asm volatile("s_waitcnt vmcnt(4)" ::: "memory");
    else if (VM == 1) asm volatile("s_waitcnt vmcnt(0)" ::: "memory");
    if (VM != 2) {
      __builtin_amdgcn_s_barrier();
      __builtin_amdgcn_sched_barrier(0);
    }
  };

  STG_B(0, 0);
  STG_A(0, 0);
  STG_B(1, 1);
  asm volatile("s_waitcnt vmcnt(4)" ::: "memory");
  __builtin_amdgcn_s_barrier();
  __builtin_amdgcn_sched_barrier(0);

  for (int it = 0; it < 15; ++it) {
    tile(2 * it, 0, true, true, 0);
    tile(2 * it + 1, 1, true, true, 0);
  }
  tile(30, 0, true, false, 1);
  tile(31, 1, false, false, 2);

  // ---- epilogue ----
  const int row_b = bm * 128 + wr * 64 + hi * 4;
  const int col_b = bn * 256 + wcn * 64 + lr;
  if (EPI == 0) {
#pragma unroll
    for (int m = 0; m < 4; ++m)
#pragma unroll
      for (int n = 0; n < 4; ++n) {
        int col = col_b + n * 16;
#pragma unroll
        for (int j = 0; j < 4; ++j) {
          int row = row_b + m * 16 + j;
          C0[(size_t)row * 2048 + col] = acc[m][n][j];
        }
      }
  } else {
    const int sel = bn >> 3;  // 0:q 1:k 2:v (2048-wide each)
#pragma unroll
    for (int m = 0; m < 4; ++m) {
#pragma unroll
      for (int n = 0; n < 4; ++n) {
        int col = col_b + n * 16;
        int hh = (col >> 7) & 15, d = col & 127;
        if (sel == 2) {
#pragma unroll
          for (int j = 0; j < 4; ++j) {
            int row = row_b + m * 16 + j;
            int b = row >> 11, s = row & 2047;
            Cv[((size_t)(b * NH + hh) * S_LEN + s) * DHD + d] = f2bf(acc[m][n][j]);
          }
        } else {
          unsigned short* dst = sel ? Ck : Cq;
          int dj = d >> 1;
          float sgn = (d & 1) ? 1.f : -1.f;
#pragma unroll
          for (int j = 0; j < 4; ++j) {
            int row = row_b + m * 16 + j;
            int b = row >> 11, s = row & 2047;
            float v = acc[m][n][j];
            float pp = __shfl_xor(v, 1);
            float cc = cosT[(s << 6) + dj];
            float sn = sinT[(s << 6) + dj];
            dst[((size_t)(b * NH + hh) * S_LEN + s) * DHD + d] = f2bf(v * cc + sgn * pp * sn);
          }
        }
      }
    }
  }
#undef STG_A
#undef STG_B
}

// ---------------- causal flash attention (R9 body: XCD-local head mapping) ----
// Q,K,V: [B][H][S][DH] bf16.  O: [B][S][H][DH] bf16.
// 1-D grid 512: lid = (hb&7) + 8*pq + 128*(hb>>3) -> XCD = lid%8 = hb&7,
// so each XCD owns 4 complete head-batches (K/V 4 MB = L2-resident).
__global__ __launch_bounds__(256) void k_flash_attn(const unsigned short* __restrict__ Qg,
                                                    const unsigned short* __restrict__ Kg,
                                                    const unsigned short* __restrict__ Vg,
                                                    unsigned short* __restrict__ Og) {
  __shared__ unsigned short K_lds[2][64 * 128];
  __shared__ unsigned short VT_lds[2][128 * 64];

  const int lid = blockIdx.x;
  const int pq = (lid >> 3) & 15;
  const int hb = ((lid >> 7) << 3) | (lid & 7);
  const int h = hb & 15, b = hb >> 4;

  const int t = threadIdx.x;
  const int lane = t & 63, wave = t >> 6;
  const int hi = lane >> 4, lr = lane & 15;

  const size_t head = (size_t)(b * NH + h) * (size_t)(S_LEN * DHD);
  const unsigned short* Q = Qg + head;
  const unsigned short* Kp = Kg + head;
  const unsigned short* Vp = Vg + head;

  const int kr0 = t >> 4;
  const int kgc = (t & 15) ^ (kr0 & 7);
  const unsigned short* Kbase = Kp + (size_t)kr0 * DHD + kgc * 8;
  const int kdst = t * 16;

  const int vdc = t & 15, vsp0 = t >> 4;
  const unsigned short* Vbase = Vp + (size_t)(2 * vsp0) * DHD + vdc * 8;
  const int bo0 = 16 * ((vsp0 >> 1) & 3) + 8 * ((vsp0 >> 3) & 1) + 4 * (vsp0 & 1);

  const float sc = 0.08838834764831845f;  // 1/sqrt(128)

  for (int pass = 0; pass < 2; ++pass) {
    const int qt = (pass == 0) ? pq : (31 - pq);
    const int nt = qt + 1;
    const int qbase = qt * 64 + wave * 16;
    const int qrow = qbase + lr;

    bf16x8 qf[4];
    {
      const unsigned short* qr_ = Q + (size_t)(qbase + lr) * DHD;
#pragma unroll
      for (int kc = 0; kc < 4; ++kc) qf[kc] = *(const bf16x8*)(qr_ + kc * 32 + hi * 8);
    }

    f32x4 of[8];
#pragma unroll
    for (int i = 0; i < 8; ++i) {
      f32x4 z = {0.f, 0.f, 0.f, 0.f};
      of[i] = z;
    }
    float mS = -INFINITY;
    float lsum = 0.f;

    {
#pragma unroll
      for (int i = 0; i < 4; ++i)
        async_cp16((char*)K_lds[0] + kdst + i * 4096, Kbase + (size_t)(16 * i) * DHD);
      ushort8 va0 = *(const ushort8*)(Vbase);
      ushort8 vb0 = *(const ushort8*)(Vbase + DHD);
      ushort8 va1 = *(const ushort8*)(Vbase + (size_t)32 * DHD);
      ushort8 vb1 = *(const ushort8*)(Vbase + (size_t)33 * DHD);
#pragma unroll
      for (int j = 0; j < 8; ++j) {
        int row = vdc * 8 + j;
        int swz = ((j ^ vdc) & 7) << 4;
        *(unsigned int*)((char*)VT_lds[0] + row * 128 + (bo0 ^ swz)) =
            (unsigned int)va0[j] | ((unsigned int)vb0[j] << 16);
        *(unsigned int*)((char*)VT_lds[0] + row * 128 + ((bo0 | 64) ^ swz)) =
            (unsigned int)va1[j] | ((unsigned int)vb1[j] << 16);
      }
    }
    __syncthreads();

    for (int tt = 0; tt < nt; ++tt) {
      const int cur = tt & 1;
      const int kv0 = tt * 64;
      const bool more = (tt + 1 < nt);
      const bool diag = (tt == qt);

      ushort8 va0, vb0, va1, vb1;
      if (more) {
        const unsigned short* ks = Kbase + (size_t)(kv0 + 64) * DHD;
#pragma unroll
        for (int i = 0; i < 4; ++i)
          async_cp16((char*)K_lds[cur ^ 1] + kdst + i * 4096, ks + (size_t)(16 * i) * DHD);
        const unsigned short* vs = Vbase + (size_t)(kv0 + 64) * DHD;
        va0 = *(const ushort8*)(vs);
        vb0 = *(const ushort8*)(vs + DHD);
        va1 = *(const ushort8*)(vs + (size_t)32 * DHD);
        vb1 = *(const ushort8*)(vs + (size_t)33 * DHD);
      }

      const char* Kb = (const char*)K_lds[cur];
      f32x4 sf[4];
#pragma unroll
      for (int n = 0; n < 4; ++n) {
        f32x4 z = {0.f, 0.f, 0.f, 0.f};
        sf[n] = z;
      }
      __builtin_amdgcn_s_setprio(1);
#pragma unroll
      for (int n = 0; n < 4; ++n) {
        const int kr = n * 16 + lr;
        const int kswz = (kr & 7) << 4;
#pragma unroll
        for (int kc = 0; kc < 4; ++kc) {
          bf16x8 kf = *(const bf16x8*)(Kb + kr * 256 + ((kc * 64 + hi * 16) ^ kswz));
          sf[n] = __builtin_amdgcn_mfma_f32_16x16x32_bf16(kf, qf[kc], sf[n], 0, 0, 0);
        }
      }
      __builtin_amdgcn_s_setprio(0);

      float p[4][4];
      float mx = -INFINITY;
      if (diag) {
#pragma unroll
        for (int n = 0; n < 4; ++n)
#pragma unroll
          for (int j = 0; j < 4; ++j) {
            int kvcol = kv0 + n * 16 + hi * 4 + j;
            float v = (kvcol > qrow) ? -INFINITY : sf[n][j];
            p[n][j] = v;
            mx = fmaxf(mx, v);
          }
      } else {
#pragma unroll
        for (int n = 0; n < 4; ++n)
#pragma unroll
          for (int j = 0; j < 4; ++j) {
            float v = sf[n][j];
            p[n][j] = v;
            mx = fmaxf(mx, v);
          }
      }
      mx = fmaxf(mx, __shfl_xor(mx, 16));
      mx = fmaxf(mx, __shfl_xor(mx, 32));
      float mn = fmaxf(mS, mx);
      float corr = __expf((mS - mn) * sc);
      mS = mn;
      float mns = mn * sc;
      float rs = 0.f;
#pragma unroll
      for (int n = 0; n < 4; ++n)
#pragma unroll
        for (int j = 0; j < 4; ++j) {
          float e = __expf(__builtin_fmaf(p[n][j], sc, -mns));
          p[n][j] = e;
          rs += e;
        }
      rs += __shfl_xor(rs, 16);
      rs += __shfl_xor(rs, 32);
      lsum = lsum * corr + rs;

      unsigned int pk[4][2];
#pragma unroll
      for (int n = 0; n < 4; ++n) {
        pk[n][0] = cvt_pk_bf16(p[n][0], p[n][1]);
        pk[n][1] = cvt_pk_bf16(p[n][2], p[n][3]);
      }

      float corrb[4];
#pragma unroll
      for (int j = 0; j < 4; ++j) corrb[j] = __shfl(corr, hi * 4 + j);
#pragma unroll
      for (int nd = 0; nd < 8; ++nd)
#pragma unroll
        for (int j = 0; j < 4; ++j) of[nd][j] *= corrb[j];

      const char* Vb = (const char*)VT_lds[cur];
      __builtin_amdgcn_s_setprio(1);
#pragma unroll
      for (int kc = 0; kc < 2; ++kc) {
        union { unsigned int u[4]; bf16x8 v; } pa;
        pa.u[0] = pk[2 * kc][0];
        pa.u[1] = pk[2 * kc][1];
        pa.u[2] = pk[2 * kc + 1][0];
        pa.u[3] = pk[2 * kc + 1][1];
#pragma unroll
        for (int nd = 0; nd < 8; ++nd) {
          const int vr = nd * 16 + lr;
          const int vswz = ((vr & 7) ^ ((vr >> 3) & 7)) << 4;
          bf16x8 vf = *(const bf16x8*)(Vb + vr * 128 + ((kc * 64 + hi * 16) ^ vswz));
          of[nd] = __builtin_amdgcn_mfma_f32_16x16x32_bf16(pa.v, vf, of[nd], 0, 0, 0);
        }
      }
      __builtin_amdgcn_s_setprio(0);

      if (more) {
        char* Vw = (char*)VT_lds[cur ^ 1];
#pragma unroll
        for (int j = 0; j < 8; ++j) {
          int row = vdc * 8 + j;
          int swz = ((j ^ vdc) & 7) << 4;
          *(unsigned int*)(Vw + row * 128 + (bo0 ^ swz)) =
              (unsigned int)va0[j] | ((unsigned int)vb0[j] << 16);
          *(unsigned int*)(Vw + row * 128 + ((bo0 | 64) ^ swz)) =
              (unsigned int)va1[j] | ((unsigned int)vb1[j] << 16);
        }
      }
      __syncthreads();
    }

    float inv[4];
#pragma unroll
    for (int j = 0; j < 4; ++j) {
      float ls = __shfl(lsum, hi * 4 + j);
      inv[j] = 1.0f / ls;
    }
#pragma unroll
    for (int nd = 0; nd < 8; ++nd)
#pragma unroll
      for (int j = 0; j < 4; ++j) {
        int qr = qbase + hi * 4 + j;
        Og[((size_t)(b * S_LEN + qr) * NH + h) * DHD + nd * 16 + lr] = f2bf(of[nd][j] * inv[j]);
      }
  }
}

// ---------------- launch ----------------
extern "C" void kernel_launch(void* const* d_in, const int* in_sizes, int n_in,
                              void* d_out, int out_size, void* d_ws, size_t ws_size,
                              hipStream_t stream) {
  const float* x  = (const float*)d_in[0];
  const float* wq = (const float*)d_in[1];
  const float* wk = (const float*)d_in[2];
  const float* wv = (const float*)d_in[3];
  const float* wo = (const float*)d_in[4];
  float* out = (float*)d_out;

  char* ws = (char*)d_ws;
  unsigned short* xb    = (unsigned short*)(ws);              // 16 MB (reused as attn out)
  unsigned short* wqT   = (unsigned short*)(ws + 16777216);   // 8 MB each -> [6144][2048]
  unsigned short* woT   = (unsigned short*)(ws + 41943040);
  unsigned short* qb    = (unsigned short*)(ws + 50331648);   // 16 MB each
  unsigned short* kb    = (unsigned short*)(ws + 67108864);
  unsigned short* vb    = (unsigned short*)(ws + 83886080);
  float*          cosT  = (float*)(ws + 100663296);           // 512 KB
  float*          sinT  = (float*)(ws + 101187584);
  unsigned short* attnb = xb;

  k_prep_all<<<12800, 256, 0, stream>>>(x, wq, wk, wv, wo, xb, wqT, cosT, sinT);

  // fused q/k/v projection: 32x24 tiles of 128x256 -> 768 blocks (3 even rounds)
  k_gemm128<1><<<768, 512, 0, stream>>>(xb, wqT, nullptr, qb, kb, vb, cosT, sinT, 6);

  // attention: 512 blocks, XCD-local head mapping (lid%8 = hb&7)
  k_flash_attn<<<512, 256, 0, stream>>>(qb, kb, vb, attnb);

  // output projection: 32x8 tiles of 128x256 -> 256 blocks (1 round)
  k_gemm128<0><<<256, 512, 0, stream>>>(attnb, woT, out, nullptr, nullptr, nullptr,
                                        nullptr, nullptr, 2);
}